// Round 3
// baseline (111.183 us; speedup 1.0000x reference)
//
#include <hip/hip_runtime.h>
#include <hip/hip_bf16.h>

typedef short v8s __attribute__((ext_vector_type(8)));
typedef float v4f __attribute__((ext_vector_type(4)));

#define NN 1024
#define MM 32
#define DD 256
#define NMROWS (NN * MM)

__device__ __forceinline__ unsigned short f2bf(float f) {
    unsigned u = __float_as_uint(f);
    unsigned r = (u + 0x7fffu + ((u >> 16) & 1u)) >> 16;
    return (unsigned short)r;
}

// Kernel 1: per-speaker scaled bf16 centroids + exact fp32 leave-one-out sigma.
__global__ __launch_bounds__(256) void k_centroid(
    const float* __restrict__ e, const float* __restrict__ wp,
    unsigned short* __restrict__ c_scaled,   // [NN][DD] = bf16(kappa * s / M)
    float* __restrict__ sig_own)             // [NMROWS] = kappa * LOO-dot (exact fp32)
{
    __shared__ float es[MM][260];    // +4 pad breaks bank aliasing
    __shared__ float s_l[DD];
    const int n = blockIdx.x, t = threadIdx.x;
    const float kappa = wp[0] * 1.44269504088896340736f;
    const float* eb0 = e + (size_t)n * MM * DD;

    for (int r = 0; r < 8; ++r) {
        int id = r * 256 + t;
        int m = id >> 6, c4 = (id & 63) << 2;
        *reinterpret_cast<float4*>(&es[m][c4]) =
            *reinterpret_cast<const float4*>(eb0 + m * DD + c4);
    }
    __syncthreads();

    {
        float s = 0.f;
        #pragma unroll
        for (int m = 0; m < MM; ++m) s += es[m][t];
        s_l[t] = s;
        c_scaled[n * DD + t] = f2bf(s * (kappa / (float)MM));
    }
    __syncthreads();

    const int m = t >> 3, j = t & 7;
    float a1 = 0.f, a2 = 0.f;
    #pragma unroll
    for (int ii = 0; ii < 32; ++ii) {
        int d = j + (ii << 3);
        float ev = es[m][d];
        a1 += ev * s_l[d];
        a2 += ev * ev;
    }
    a1 += __shfl_xor(a1, 1, 8); a1 += __shfl_xor(a1, 2, 8); a1 += __shfl_xor(a1, 4, 8);
    a2 += __shfl_xor(a2, 1, 8); a2 += __shfl_xor(a2, 2, 8); a2 += __shfl_xor(a2, 4, 8);
    if (j == 0)
        sig_own[n * MM + m] = kappa * (a1 - a2) * (1.0f / (float)(MM - 1));
}

// Kernel 2: fused sim-GEMM + exp-sum + per-row LSE + loss reduction.
// Block = 512 thr = 8 waves; wave handles 16 rows; block covers all 1024 cols.
__global__ __launch_bounds__(512, 2) void k_gemm_loss(
    const float* __restrict__ e,
    const unsigned short* __restrict__ c_scaled,
    const float* __restrict__ sig_own,
    float* __restrict__ out)
{
    __shared__ unsigned short lc[64 * 264];  // 64 centroids x (256+8 pad) bf16
    __shared__ float wsum[8];
    const int t = threadIdx.x;
    const int wave = t >> 6, lane = t & 63;
    const int r16 = lane & 15, q = lane >> 4;
    const int row0 = blockIdx.x * 128;
    const int myrow0 = row0 + wave * 16;     // 16-row tile, single speaker
    const int spk = myrow0 >> 5;

    // A fragments from fp32 e, converted in-register: A[m=r16][k=q*8+j]
    v8s A[8];
    {
        const float* ap = e + (size_t)(myrow0 + r16) * DD + q * 8;
        #pragma unroll
        for (int kb = 0; kb < 8; ++kb) {
            float4 f0 = *reinterpret_cast<const float4*>(ap + kb * 32);
            float4 f1 = *reinterpret_cast<const float4*>(ap + kb * 32 + 4);
            v8s a;
            a[0] = (short)f2bf(f0.x); a[1] = (short)f2bf(f0.y);
            a[2] = (short)f2bf(f0.z); a[3] = (short)f2bf(f0.w);
            a[4] = (short)f2bf(f1.x); a[5] = (short)f2bf(f1.y);
            a[6] = (short)f2bf(f1.z); a[7] = (short)f2bf(f1.w);
            A[kb] = a;
        }
    }

    // staging: thread t owns chunks {t + r*512}: crow = (t>>5)+r*16, ch = t&31
    const unsigned short* gbase = c_scaled + (size_t)(t >> 5) * DD + (t & 31) * 8;
    unsigned short* lbase = &lc[(t >> 5) * 264 + (t & 31) * 8];

    v8s pf[2][4];
    #pragma unroll
    for (int r = 0; r < 4; ++r)
        pf[0][r] = *reinterpret_cast<const v8s*>(gbase + (size_t)(r * 16) * DD);

    float sums[4] = {};
    for (int it = 0; it < 16; ++it) {
        const int cur = it & 1, nxt = cur ^ 1;
        __syncthreads();                     // previous tile's consumers done
        #pragma unroll
        for (int r = 0; r < 4; ++r)
            *reinterpret_cast<v8s*>(lbase + r * 16 * 264) = pf[cur][r];
        __syncthreads();
        if (it < 15) {                       // prefetch next tile under MFMA shadow
            const unsigned short* gp = gbase + (size_t)((it + 1) * 64) * DD;
            #pragma unroll
            for (int r = 0; r < 4; ++r)
                pf[nxt][r] = *reinterpret_cast<const v8s*>(gp + (size_t)(r * 16) * DD);
        }

        v4f acc[4] = {};
        #pragma unroll
        for (int kb = 0; kb < 8; ++kb) {
            v8s b[4];
            #pragma unroll
            for (int ct = 0; ct < 4; ++ct)
                b[ct] = *reinterpret_cast<const v8s*>(
                    &lc[(ct * 16 + r16) * 264 + kb * 32 + q * 8]);
            #pragma unroll
            for (int ct = 0; ct < 4; ++ct)
                acc[ct] = __builtin_amdgcn_mfma_f32_16x16x32_bf16(
                    A[kb], b[ct], acc[ct], 0, 0, 0);
        }
        #pragma unroll
        for (int ct = 0; ct < 4; ++ct) {
            const int col = it * 64 + ct * 16 + r16;   // D layout: col = lane&15
            const bool skip = (col == spk);
            #pragma unroll
            for (int i = 0; i < 4; ++i) {
                float ev = __builtin_amdgcn_exp2f(acc[ct][i]);
                sums[i] += skip ? 0.f : ev;
            }
        }
    }

    // reduce exp-sums over the 16 col-lanes; D row = q*4 + reg
    #pragma unroll
    for (int i = 0; i < 4; ++i) {
        float v = sums[i];
        v += __shfl_xor(v, 1, 16);
        v += __shfl_xor(v, 2, 16);
        v += __shfl_xor(v, 4, 16);
        v += __shfl_xor(v, 8, 16);
        sums[i] = v;
    }

    // per-row loss: lr = ln2 * (log2(S + 2^so) - so); rows myrow0 + q*4 + i
    float lr = 0.f;
    #pragma unroll
    for (int i = 0; i < 4; ++i) {
        const int row = myrow0 + q * 4 + i;
        float so = sig_own[row];
        float Sp = sums[i] + __builtin_amdgcn_exp2f(so);
        lr += __builtin_amdgcn_logf(Sp) - so;
    }
    lr *= 0.69314718055994530942f;
    lr += __shfl_xor(lr, 16, 64);            // sum across the 4 q-groups
    lr += __shfl_xor(lr, 32, 64);
    if (lane == 0) wsum[wave] = lr;
    __syncthreads();
    if (t == 0) {
        float tot = 0.f;
        #pragma unroll
        for (int w8 = 0; w8 < 8; ++w8) tot += wsum[w8];
        atomicAdd(out, tot * (1.0f / (float)NMROWS));
    }
}

extern "C" void kernel_launch(void* const* d_in, const int* in_sizes, int n_in,
                              void* d_out, int out_size, void* d_ws, size_t ws_size,
                              hipStream_t stream)
{
    const float* e = (const float*)d_in[0];
    const float* w = (const float*)d_in[1];
    char* ws = (char*)d_ws;

    unsigned short* c_scaled = (unsigned short*)ws;            // 512 KB
    float* sig_own = (float*)(ws + (size_t)(1 << 19));         // 128 KB
    float* outf = (float*)d_out;

    hipMemsetAsync(d_out, 0, sizeof(float), stream);
    hipLaunchKernelGGL(k_centroid, dim3(NN), dim3(256), 0, stream,
                       e, w, c_scaled, sig_own);
    hipLaunchKernelGGL(k_gemm_loss, dim3(NMROWS / 128), dim3(512), 0, stream,
                       e, c_scaled, sig_own, outf);
}